// Round 1
// baseline (11067.101 us; speedup 1.0000x reference)
//
#include <hip/hip_runtime.h>
#include <hip/hip_cooperative_groups.h>

// LIF recurrent network, persistent cooperative kernel.
// 128 WGs x 1024 threads. WG g owns columns [g*64, g*64+64).
// Wave w of a WG accumulates spike segments sg (sg % 16 == w) into registers,
// LDS-reduce, wave 0 does the pointwise update + deterministic spike
// compaction into a double-buffered per-WG spike list. One grid sync / step.

namespace cg = cooperative_groups;

constexpr int N_NEUR = 8192;
constexpr int NWG    = 128;   // workgroups == producer segments
constexpr int SEG    = 64;    // neurons per WG / segment
constexpr int NWAVES = 16;    // waves per WG

__global__ __launch_bounds__(1024) void lif_kernel(
    const float* __restrict__ inputs,
    const float* __restrict__ Wt,          // [N][N] row-major, row = presynaptic
    const int*   __restrict__ ntypes,      // {+1,-1}
    const float* __restrict__ pEw,
    const float* __restrict__ pIw,
    const float* __restrict__ pEvth,
    const float* __restrict__ pIvth,
    const int*   __restrict__ pnsteps,
    float*       __restrict__ out,         // (2, n_steps, N) f32
    float*       __restrict__ scale,       // ws: [N] f32
    unsigned short* __restrict__ list0,    // ws: [N] u16 (segmented, 64/WG)
    unsigned short* __restrict__ list1,
    unsigned int* __restrict__ cnt0,       // ws: [NWG]
    unsigned int* __restrict__ cnt1)
{
    cg::grid_group grid = cg::this_grid();

    const int g    = blockIdx.x;
    const int tid  = threadIdx.x;
    const int w    = tid >> 6;
    const int lane = tid & 63;
    const int c    = g * SEG + lane;       // column this lane accumulates

    const float Ew   = *pEw;
    const float Iw   = *pIw;
    const float Evth = *pEvth;
    const float Ivth = *pIvth;
    const int n_steps = *pnsteps;

    const float alpha = expf(-0.1f);       // exp(-DT/TAU_M), matches reference
    const float beta  = expf(-0.2f);       // exp(-DT/TAU_I)
    const float omal  = 1.0f - alpha;

    // ---- setup: presynaptic scale (Dale sign * E/I weight), zero counts ----
    const int gidx = g * 1024 + tid;
    if (gidx < N_NEUR) {
        int ty = ntypes[gidx];
        scale[gidx] = (ty == 1) ? Ew : -Iw;
    }
    if (gidx < NWG) cnt0[gidx] = 0;

    // per-neuron state, held by wave 0 (tid < 64)
    float v = 0.0f, I = 0.0f, vth = 0.0f, inp = 0.0f;
    if (tid < SEG) {
        int ty = ntypes[c];
        vth = (ty == 1) ? Evth : Ivth;
        inp = inputs[c];
    }

    __shared__ float red[NWAVES][SEG];

    grid.sync();

    for (int t = 0; t < n_steps; ++t) {
        const unsigned int*   cnts = (t & 1) ? cnt1 : cnt0;
        const unsigned short* lst  = (t & 1) ? list1 : list0;
        unsigned int*   ncnts = (t & 1) ? cnt0 : cnt1;
        unsigned short* nlst  = (t & 1) ? list0 : list1;

        // ---- gather spiking rows: 4 independent accumulator chains ----
        float a0 = 0.f, a1 = 0.f, a2 = 0.f, a3 = 0.f;
        for (int sg = w; sg < NWG; sg += NWAVES) {
            const int cnt = (int)cnts[sg];
            const unsigned short* seg = lst + (sg << 6);
            int k = 0;
            for (; k + 4 <= cnt; k += 4) {
                const int j0 = seg[k], j1 = seg[k + 1];
                const int j2 = seg[k + 2], j3 = seg[k + 3];
                a0 = fmaf(scale[j0], Wt[(size_t)j0 * N_NEUR + c], a0);
                a1 = fmaf(scale[j1], Wt[(size_t)j1 * N_NEUR + c], a1);
                a2 = fmaf(scale[j2], Wt[(size_t)j2 * N_NEUR + c], a2);
                a3 = fmaf(scale[j3], Wt[(size_t)j3 * N_NEUR + c], a3);
            }
            for (; k < cnt; ++k) {
                const int j = seg[k];
                a0 = fmaf(scale[j], Wt[(size_t)j * N_NEUR + c], a0);
            }
        }
        red[w][lane] = (a0 + a1) + (a2 + a3);
        __syncthreads();

        // ---- pointwise update + spike compaction (wave 0 only) ----
        if (tid < SEG) {
            float rec = 0.0f;
            #pragma unroll
            for (int ww = 0; ww < NWAVES; ++ww) rec += red[ww][tid];

            I = beta * I + rec;
            const float vn = alpha * v + omal * (I + inp);
            const bool spk = (vn >= vth);
            v = spk ? 0.0f : vn;

            out[(size_t)t * N_NEUR + c] = v;
            out[(size_t)n_steps * N_NEUR + (size_t)t * N_NEUR + c] = spk ? 1.0f : 0.0f;

            const unsigned long long m = __ballot(spk);
            if (spk) {
                const int pos = __popcll(m & ((1ull << lane) - 1ull));
                nlst[(g << 6) + pos] = (unsigned short)c;
            }
            if (lane == 0) ncnts[g] = (unsigned int)__popcll(m);
        }

        grid.sync();  // spike list visible grid-wide; red[] safe to reuse
    }
}

extern "C" void kernel_launch(void* const* d_in, const int* in_sizes, int n_in,
                              void* d_out, int out_size, void* d_ws, size_t ws_size,
                              hipStream_t stream) {
    const float* inputs = (const float*)d_in[0];
    const float* Wt     = (const float*)d_in[1];
    const int*   ntypes = (const int*)d_in[2];
    const float* pEw    = (const float*)d_in[3];
    const float* pIw    = (const float*)d_in[4];
    const float* pEvth  = (const float*)d_in[5];
    const float* pIvth  = (const float*)d_in[6];
    const int*   pnst   = (const int*)d_in[7];
    float* out = (float*)d_out;

    char* ws = (char*)d_ws;
    float*          scale = (float*)(ws);                    // 32 KiB
    unsigned short* list0 = (unsigned short*)(ws + 32768);   // 16 KiB
    unsigned short* list1 = (unsigned short*)(ws + 49152);   // 16 KiB
    unsigned int*   cnt0  = (unsigned int*)(ws + 65536);     // 512 B
    unsigned int*   cnt1  = (unsigned int*)(ws + 66048);     // 512 B

    void* args[] = { (void*)&inputs, (void*)&Wt, (void*)&ntypes,
                     (void*)&pEw, (void*)&pIw, (void*)&pEvth, (void*)&pIvth,
                     (void*)&pnst, (void*)&out,
                     (void*)&scale, (void*)&list0, (void*)&list1,
                     (void*)&cnt0, (void*)&cnt1 };

    hipLaunchCooperativeKernel((const void*)lif_kernel, dim3(NWG), dim3(1024),
                               args, 0, stream);
}

// Round 2
// 3487.141 us; speedup vs baseline: 3.1737x; 3.1737x over previous
//
#include <hip/hip_runtime.h>

// LIF recurrent network as 500 chained graph nodes (one kernel per step).
// Spike exchange via a 1 KB double-buffered global bitmask (128 x u64).
// Step kernel: 128 WGs x 256 threads; WG g owns neurons [g*64, g*64+64).
// Wave 0 decodes the full mask (2 words/lane, shfl-scan, deterministic
// ascending order) into an LDS list; 4 waves split the row gather; LDS
// reduce; wave 0 does the pointwise update, trace writes, and ballots the
// next mask word. Inter-kernel dependency provides the global sync.

constexpr int N_NEUR  = 8192;
constexpr int NWORDS  = N_NEUR / 64;   // 128 mask words
constexpr int NWG     = 128;           // step-kernel workgroups, 64 cols each
constexpr int TPB     = 256;           // 4 waves
constexpr int N_STEPS = 500;           // reference N_STEPS (kernels self-guard)

__global__ __launch_bounds__(256) void lif_init(
    const int*   __restrict__ ntypes,
    const float* __restrict__ pEw,
    const float* __restrict__ pIw,
    float* __restrict__ scale,
    float* __restrict__ v,
    float* __restrict__ I,
    unsigned long long* __restrict__ mask0,
    unsigned long long* __restrict__ mask1)
{
    const int i = blockIdx.x * blockDim.x + threadIdx.x;
    if (i < N_NEUR) {
        scale[i] = (ntypes[i] == 1) ? *pEw : -(*pIw);
        v[i] = 0.0f;
        I[i] = 0.0f;
    }
    if (i < NWORDS) { mask0[i] = 0ull; mask1[i] = 0ull; }
}

__global__ __launch_bounds__(TPB) void lif_step(
    const float* __restrict__ inputs,
    const float* __restrict__ Wt,          // [N][N] row-major, row = presyn
    const int*   __restrict__ ntypes,
    const float* __restrict__ pEvth,
    const float* __restrict__ pIvth,
    const int*   __restrict__ pnsteps,
    float* __restrict__ out,               // (2, n_steps, N) f32
    const float* __restrict__ scale,
    float* __restrict__ v,
    float* __restrict__ I,
    const unsigned long long* __restrict__ mask_in,
    unsigned long long* __restrict__ mask_out,
    int t)
{
    const int n_steps = *pnsteps;
    if (t >= n_steps) return;

    const int tid  = threadIdx.x;
    const int g    = blockIdx.x;
    const int w    = tid >> 6;
    const int lane = tid & 63;
    const int c    = g * 64 + lane;        // column owned by this lane

    __shared__ unsigned short s_idx[N_NEUR];
    __shared__ float          s_scl[N_NEUR];
    __shared__ float          s_red[4][64];
    __shared__ int            s_n;

    // per-neuron state for the update (wave 0). Loads issue before the mask
    // wait; results consumed only after the gather -> latency hidden.
    float v_old = 0.f, I_old = 0.f, inp = 0.f, vth = 0.f;

    if (tid < 64) {
        // ---- decode: 2 mask words per lane, deterministic ascending order ----
        unsigned long long w0 = mask_in[2 * lane];
        unsigned long long w1 = mask_in[2 * lane + 1];

        v_old = v[c];
        I_old = I[c];
        inp   = inputs[c];
        vth   = (ntypes[c] == 1) ? *pEvth : *pIvth;

        const int cnt = __popcll(w0) + __popcll(w1);
        int off = cnt;
        #pragma unroll
        for (int d = 1; d < 64; d <<= 1) {
            const int u = __shfl_up(off, d);
            if (lane >= d) off += u;
        }
        off -= cnt;                        // exclusive prefix
        if (lane == 63) s_n = off + cnt;

        int p = off;
        const int base0 = (2 * lane) * 64;
        while (w0) {
            const int b = __builtin_ctzll(w0); w0 &= w0 - 1;
            const int j = base0 + b;
            s_idx[p] = (unsigned short)j;
            s_scl[p] = scale[j];
            ++p;
        }
        const int base1 = base0 + 64;
        while (w1) {
            const int b = __builtin_ctzll(w1); w1 &= w1 - 1;
            const int j = base1 + b;
            s_idx[p] = (unsigned short)j;
            s_scl[p] = scale[j];
            ++p;
        }
    }
    __syncthreads();

    // ---- gather: 4 waves split the spike list round-robin, 4 ILP chains ----
    const int n = s_n;
    float a0 = 0.f, a1 = 0.f, a2 = 0.f, a3 = 0.f;
    int k = w;
    for (; k + 12 < n; k += 16) {
        const int j0 = s_idx[k],     j1 = s_idx[k + 4];
        const int j2 = s_idx[k + 8], j3 = s_idx[k + 12];
        a0 = fmaf(s_scl[k],      Wt[(size_t)j0 * N_NEUR + c], a0);
        a1 = fmaf(s_scl[k + 4],  Wt[(size_t)j1 * N_NEUR + c], a1);
        a2 = fmaf(s_scl[k + 8],  Wt[(size_t)j2 * N_NEUR + c], a2);
        a3 = fmaf(s_scl[k + 12], Wt[(size_t)j3 * N_NEUR + c], a3);
    }
    for (; k < n; k += 4)
        a0 = fmaf(s_scl[k], Wt[(size_t)s_idx[k] * N_NEUR + c], a0);
    s_red[w][lane] = (a0 + a1) + (a2 + a3);
    __syncthreads();

    // ---- pointwise update + trace writes + next-mask ballot (wave 0) ----
    if (tid < 64) {
        const float rec = (s_red[0][lane] + s_red[1][lane]) +
                          (s_red[2][lane] + s_red[3][lane]);

        const float alpha = expf(-0.1f);   // exp(-DT/TAU_M)
        const float beta  = expf(-0.2f);   // exp(-DT/TAU_I)

        const float I_new = beta * I_old + rec;
        const float vn    = alpha * v_old + (1.0f - alpha) * (I_new + inp);
        const bool  spk   = (vn >= vth);
        const float vr    = spk ? 0.0f : vn;

        out[(size_t)t * N_NEUR + c] = vr;
        out[(size_t)n_steps * N_NEUR + (size_t)t * N_NEUR + c] = spk ? 1.0f : 0.0f;
        v[c] = vr;
        I[c] = I_new;

        const unsigned long long m = __ballot(spk);
        if (lane == 0) mask_out[g] = m;
    }
}

extern "C" void kernel_launch(void* const* d_in, const int* in_sizes, int n_in,
                              void* d_out, int out_size, void* d_ws, size_t ws_size,
                              hipStream_t stream) {
    const float* inputs = (const float*)d_in[0];
    const float* Wt     = (const float*)d_in[1];
    const int*   ntypes = (const int*)d_in[2];
    const float* pEw    = (const float*)d_in[3];
    const float* pIw    = (const float*)d_in[4];
    const float* pEvth  = (const float*)d_in[5];
    const float* pIvth  = (const float*)d_in[6];
    const int*   pnst   = (const int*)d_in[7];
    float* out = (float*)d_out;

    char* ws = (char*)d_ws;
    float*              scale = (float*)(ws);                       // 32 KiB
    float*              v     = (float*)(ws + 32768);               // 32 KiB
    float*              I     = (float*)(ws + 65536);               // 32 KiB
    unsigned long long* mask0 = (unsigned long long*)(ws + 98304);  // 1 KiB
    unsigned long long* mask1 = (unsigned long long*)(ws + 99328);  // 1 KiB

    lif_init<<<dim3((N_NEUR + 255) / 256), dim3(256), 0, stream>>>(
        ntypes, pEw, pIw, scale, v, I, mask0, mask1);

    for (int t = 0; t < N_STEPS; ++t) {
        const unsigned long long* min_  = (t & 1) ? mask1 : mask0;
        unsigned long long*       mout_ = (t & 1) ? mask0 : mask1;
        lif_step<<<dim3(NWG), dim3(TPB), 0, stream>>>(
            inputs, Wt, ntypes, pEvth, pIvth, pnst,
            out, scale, v, I, min_, mout_, t);
    }
}

// Round 3
// 3193.418 us; speedup vs baseline: 3.4656x; 1.0920x over previous
//
#include <hip/hip_runtime.h>

// LIF recurrent network as 500 chained graph nodes (one kernel per step).
// Spike exchange via a 1 KB double-buffered global bitmask (128 x u64).
// Step kernel: 128 WGs x 256 threads; WG g owns neurons [g*64, g*64+64).
// Critical-path minimized: mask load issues first; scale[] preloads into LDS
// (coalesced float4) while the mask is in flight; decode is 128-lane-parallel
// (1 word/lane, shfl-scan); n_steps is consumed only at the write phase.

constexpr int N_NEUR  = 8192;
constexpr int NWORDS  = N_NEUR / 64;   // 128 mask words
constexpr int NWG     = 128;           // step-kernel workgroups, 64 cols each
constexpr int TPB     = 256;           // 4 waves
constexpr int N_STEPS = 500;           // reference N_STEPS (writes self-guard)

__global__ __launch_bounds__(256) void lif_init(
    const int*   __restrict__ ntypes,
    const float* __restrict__ pEw,
    const float* __restrict__ pIw,
    float* __restrict__ scale,
    float* __restrict__ v,
    float* __restrict__ I,
    unsigned long long* __restrict__ mask0,
    unsigned long long* __restrict__ mask1)
{
    const int i = blockIdx.x * blockDim.x + threadIdx.x;
    if (i < N_NEUR) {
        scale[i] = (ntypes[i] == 1) ? *pEw : -(*pIw);
        v[i] = 0.0f;
        I[i] = 0.0f;
    }
    if (i < NWORDS) { mask0[i] = 0ull; mask1[i] = 0ull; }
}

__global__ __launch_bounds__(TPB) void lif_step(
    const float* __restrict__ inputs,
    const float* __restrict__ Wt,          // [N][N] row-major, row = presyn
    const int*   __restrict__ ntypes,
    const float* __restrict__ pEvth,
    const float* __restrict__ pIvth,
    const int*   __restrict__ pnsteps,
    float* __restrict__ out,               // (2, n_steps, N) f32
    const float* __restrict__ scale,
    float* __restrict__ v,
    float* __restrict__ I,
    const unsigned long long* __restrict__ mask_in,
    unsigned long long* __restrict__ mask_out,
    int t)
{
    const int tid  = threadIdx.x;
    const int g    = blockIdx.x;
    const int w    = tid >> 6;
    const int lane = tid & 63;
    const int c    = (g << 6) + lane;      // column owned by this lane

    __shared__ float          s_scale[N_NEUR];   // 32 KiB
    __shared__ unsigned short s_idx[N_NEUR];     // 16 KiB
    __shared__ float          s_red[4][64];
    __shared__ int            s_ws[2];

    // ---- issue the critical-path load first ----
    unsigned long long word = 0ull;
    if (tid < NWORDS) word = mask_in[tid];

    // ---- independent preloads, overlapped with the mask latency ----
    const float4* sc4 = (const float4*)scale;
    float4*       ss4 = (float4*)s_scale;
    #pragma unroll
    for (int i = 0; i < 8; ++i)
        ss4[tid + (i << 8)] = sc4[tid + (i << 8)];   // 8192 floats, coalesced

    float v_old = 0.f, I_old = 0.f, inp = 0.f, vth = 0.f;
    if (tid < 64) {
        v_old = v[c];
        I_old = I[c];
        inp   = inputs[c];
        vth   = (ntypes[c] == 1) ? *pEvth : *pIvth;
    }
    const int n_steps = *pnsteps;          // consumed only at the write phase

    // ---- 128-lane-parallel decode: 1 word/lane, deterministic order ----
    int cnt = 0;
    if (tid < NWORDS) cnt = __popcll(word);
    int incl = cnt;
    #pragma unroll
    for (int d = 1; d < 64; d <<= 1) {
        const int u = __shfl_up(incl, d);
        if (lane >= d) incl += u;
    }
    if (w < 2 && lane == 63) s_ws[w] = incl;
    __syncthreads();

    const int n = s_ws[0] + s_ws[1];
    if (tid < NWORDS) {
        int p = ((w == 1) ? s_ws[0] : 0) + incl - cnt;   // exclusive offset
        const int base = tid << 6;
        while (word) {
            const int b = __builtin_ctzll(word); word &= word - 1;
            s_idx[p++] = (unsigned short)(base + b);
        }
    }
    __syncthreads();

    // ---- gather: 4 waves split the spike list (stride 4), 4 ILP chains ----
    float a0 = 0.f, a1 = 0.f, a2 = 0.f, a3 = 0.f;
    int k = w;
    for (; k + 12 < n; k += 16) {
        const int j0 = s_idx[k],     j1 = s_idx[k + 4];
        const int j2 = s_idx[k + 8], j3 = s_idx[k + 12];
        a0 = fmaf(s_scale[j0], Wt[(size_t)j0 * N_NEUR + c], a0);
        a1 = fmaf(s_scale[j1], Wt[(size_t)j1 * N_NEUR + c], a1);
        a2 = fmaf(s_scale[j2], Wt[(size_t)j2 * N_NEUR + c], a2);
        a3 = fmaf(s_scale[j3], Wt[(size_t)j3 * N_NEUR + c], a3);
    }
    for (; k < n; k += 4) {
        const int j = s_idx[k];
        a0 = fmaf(s_scale[j], Wt[(size_t)j * N_NEUR + c], a0);
    }
    s_red[w][lane] = (a0 + a1) + (a2 + a3);
    __syncthreads();

    // ---- pointwise update + trace writes + next-mask ballot (wave 0) ----
    if (tid < 64) {
        const float rec = (s_red[0][lane] + s_red[1][lane]) +
                          (s_red[2][lane] + s_red[3][lane]);

        const float alpha = expf(-0.1f);   // exp(-DT/TAU_M)
        const float beta  = expf(-0.2f);   // exp(-DT/TAU_I)

        const float I_new = beta * I_old + rec;
        const float vn    = alpha * v_old + (1.0f - alpha) * (I_new + inp);
        const bool  spk   = (vn >= vth);
        const float vr    = spk ? 0.0f : vn;

        if (t < n_steps) {
            out[(size_t)t * N_NEUR + c] = vr;
            out[(size_t)n_steps * N_NEUR + (size_t)t * N_NEUR + c] = spk ? 1.0f : 0.0f;
            v[c] = vr;
            I[c] = I_new;
            const unsigned long long m = __ballot(spk);
            if (lane == 0) mask_out[g] = m;
        }
    }
}

extern "C" void kernel_launch(void* const* d_in, const int* in_sizes, int n_in,
                              void* d_out, int out_size, void* d_ws, size_t ws_size,
                              hipStream_t stream) {
    const float* inputs = (const float*)d_in[0];
    const float* Wt     = (const float*)d_in[1];
    const int*   ntypes = (const int*)d_in[2];
    const float* pEw    = (const float*)d_in[3];
    const float* pIw    = (const float*)d_in[4];
    const float* pEvth  = (const float*)d_in[5];
    const float* pIvth  = (const float*)d_in[6];
    const int*   pnst   = (const int*)d_in[7];
    float* out = (float*)d_out;

    char* ws = (char*)d_ws;
    float*              scale = (float*)(ws);                       // 32 KiB
    float*              v     = (float*)(ws + 32768);               // 32 KiB
    float*              I     = (float*)(ws + 65536);               // 32 KiB
    unsigned long long* mask0 = (unsigned long long*)(ws + 98304);  // 1 KiB
    unsigned long long* mask1 = (unsigned long long*)(ws + 99328);  // 1 KiB

    lif_init<<<dim3((N_NEUR + 255) / 256), dim3(256), 0, stream>>>(
        ntypes, pEw, pIw, scale, v, I, mask0, mask1);

    for (int t = 0; t < N_STEPS; ++t) {
        const unsigned long long* min_  = (t & 1) ? mask1 : mask0;
        unsigned long long*       mout_ = (t & 1) ? mask0 : mask1;
        lif_step<<<dim3(NWG), dim3(TPB), 0, stream>>>(
            inputs, Wt, ntypes, pEvth, pIvth, pnst,
            out, scale, v, I, min_, mout_, t);
    }
}